// Round 28
// baseline (890.471 us; speedup 1.0000x reference)
//
#include <hip/hip_runtime.h>
#include <math.h>

constexpr int Bn = 32, Sn = 512, Hn = 768, NHn = 12, DHn = 64, INTERn = 3072, En = 8;

typedef __attribute__((ext_vector_type(4))) float f32x4;
typedef __attribute__((ext_vector_type(8))) short short8;
typedef __attribute__((ext_vector_type(4))) int int4v;

__device__ inline unsigned short f2b(float x) {
  unsigned u = __builtin_bit_cast(unsigned, x);
  return (unsigned short)((u + 0x7fffu + ((u >> 16) & 1u)) >> 16);
}
__device__ inline float b2f(unsigned short u) {
  unsigned x = ((unsigned)u) << 16;
  return __builtin_bit_cast(float, x);
}
__device__ inline unsigned packpair(float a, float b) {
  return (unsigned)f2b(a) | ((unsigned)f2b(b) << 16);
}
__device__ inline short8 pack8(const float* p) {
  int4v w;
  w.x = (int)packpair(p[0], p[1]); w.y = (int)packpair(p[2], p[3]);
  w.z = (int)packpair(p[4], p[5]); w.w = (int)packpair(p[6], p[7]);
  return __builtin_bit_cast(short8, w);
}
__device__ inline float fast_gelu(float u) {
  float z = 0.7978845608028654f * (u + 0.044715f * u * u * u);
  float e = __expf(2.f * z);
  float t = 1.f - 2.f / (e + 1.f);
  return 0.5f * u * (1.f + t);
}
// async global->LDS, 16B per lane; lds base must be wave-uniform (HW adds lane*16)
__device__ inline void gload16(const void* g, void* l) {
  __builtin_amdgcn_global_load_lds(
      (const __attribute__((address_space(1))) unsigned int*)g,
      (__attribute__((address_space(3))) unsigned int*)l, 16, 0, 0);
}

// ---------------- standalone route: raw-gram + centering + 3-sweep Jacobi + kmeans(early-exit) ----------------
// (3 sweeps = verified routing floor — r20. 4-wave barriers = floor structure — r25.
//  r26: fused two-sided update, 3 barriers/round (144->138.5 us, bit-identical).
//  r27: per-thread redundant rotation computation from the tournament schedule —
//  removes the tid<16 setup phase + 1 barrier (2 barriers/round). Rotation params
//  computed from the SAME A[p][p],A[q][q],A[p][q] cells with the byte-identical
//  expression -> same f32 bits as the LDS-broadcast version.)

struct RouteSM {
  float A[32][33];
  float V[32][33];
  float Y[32][32];
  float C[8][32];
  float D[32][8];
  float lam[32];
  float lam2[32];
  float rs[32];
  float gsum;
  int ord[32];
  int asg[32];
  int cnt[8];
  int Psh;
  int chg;
};

// tournament pair of index x at round rnd (matches the original tid<16 schedule:
// pair0 = (rnd, 31); pair t = ((rnd+t)%31, (rnd+31-t)%31), t=1..15)
__device__ inline void jrot(const RouteSM& S, int rnd, int x,
                            int& prt, int& isP, float& cc, float& ss) {
  int p, q;
  if (x == 31) { p = rnd; q = 31; }
  else {
    int d = x - rnd; if (d < 0) d += 31;
    if (d == 0) { p = x; q = 31; }
    else if (d <= 15) { p = x; q = rnd + 31 - d; if (q >= 31) q -= 31; }
    else { q = x; p = rnd + 31 - d; if (p >= 31) p -= 31; }
  }
  float app = S.A[p][p], aqq = S.A[q][q], apq = S.A[p][q];
  cc = 1.f; ss = 0.f;
  if (fabsf(apq) > 1e-18f) {
    float tau = (aqq - app) / (2.f * apq);
    float t = 1.f / (fabsf(tau) + sqrtf(1.f + tau * tau));
    if (tau < 0.f) t = -t;
    cc = 1.f / sqrtf(1.f + t * t);
    ss = t * cc;
  }
  prt = (x == p) ? q : p;
  isP = (x == p) ? 1 : 0;
}

__global__ __launch_bounds__(256) void route_kernel(const float* __restrict__ cbuf, int* __restrict__ r) {
  __shared__ __align__(16) char smem[24576];
  RouteSM& S = *reinterpret_cast<RouteSM*>(smem);
  int tid = threadIdx.x;
  int i0 = tid >> 5, j256 = tid & 31;

  // ---- raw Gram (256 threads): A[i][j] = dot(raw_i, raw_j) ----
  {
    float s[4] = {0.f, 0.f, 0.f, 0.f};
    const float* cj = cbuf + (size_t)j256 * Hn;
    for (int t = 0; t < Hn; t += 4) {
      float4 y = *(const float4*)(cj + t);
#pragma unroll
      for (int e = 0; e < 4; e++) {
        const float* ci = cbuf + (size_t)(i0 + 8 * e) * Hn;
        float4 x = *(const float4*)(ci + t);
        s[e] += x.x * y.x + x.y * y.y + x.z * y.z + x.w * y.w;
      }
    }
#pragma unroll
    for (int e = 0; e < 4; e++) {
      int i = i0 + 8 * e;
      S.A[i][j256] = s[e];
      S.V[i][j256] = (i == j256) ? 1.f : 0.f;
    }
  }
  __syncthreads();
  // ---- center the Gram: Gc = G - (rs_i + rs_j)/32 + gs/1024 (exact identity) ----
  if (tid < 32) {
    float s = 0.f;
    for (int jj = 0; jj < 32; jj++) s += S.A[tid][jj];
    S.rs[tid] = s;
  }
  __syncthreads();
  if (tid == 0) {
    float g = 0.f;
    for (int a = 0; a < 32; a++) g += S.rs[a];
    S.gsum = g * (1.f / 1024.f);
  }
  __syncthreads();
  {
    float corr = S.gsum;
#pragma unroll
    for (int e = 0; e < 4; e++) {
      int i = i0 + 8 * e;
      S.A[i][j256] = S.A[i][j256] - (S.rs[i] + S.rs[j256]) * (1.f / 32.f) + corr;
    }
  }
  __syncthreads();

  // ---- Jacobi: fixed 3 sweeps, per-thread rotations, 2 barriers/round ----
  for (int sweep = 0; sweep < 3; sweep++) {
    for (int rnd = 0; rnd < 31; rnd++) {
      int pj, ipj; float cc, ss;
      jrot(S, rnd, j256, pj, ipj, cc, ss);
      int pi2e[4], ipie[4]; float c2e[4], s2e[4];
#pragma unroll
      for (int e = 0; e < 4; e++) jrot(S, rnd, i0 + 8 * e, pi2e[e], ipie[e], c2e[e], s2e[e]);
      float nb[4], nv[4];
#pragma unroll
      for (int e = 0; e < 4; e++) {
        int i = i0 + 8 * e;
        // col update of own row (== r26 t1):
        float a = S.A[i][j256], a2 = S.A[i][pj];
        float t1 = ipj ? (cc * a - ss * a2) : (ss * a2 + cc * a);
        float v1 = S.V[i][j256], v2 = S.V[i][pj];
        nv[e] = ipj ? (cc * v1 - ss * v2) : (ss * v2 + cc * v1);
        // col update of partner row (== r26 t2):
        float b = S.A[pi2e[e]][j256], b2 = S.A[pi2e[e]][pj];
        float t2 = ipj ? (cc * b - ss * b2) : (ss * b2 + cc * b);
        // row update:
        nb[e] = ipie[e] ? (c2e[e] * t1 - s2e[e] * t2) : (s2e[e] * t2 + c2e[e] * t1);
      }
      __syncthreads();
#pragma unroll
      for (int e = 0; e < 4; e++) { int i = i0 + 8 * e; S.A[i][j256] = nb[e]; S.V[i][j256] = nv[e]; }
      __syncthreads();
    }
  }

  // ---- sort / keep-rule / k-means (verified; early-exit is exact) ----
  if (tid < 32) S.lam[tid] = S.A[tid][tid];
  __syncthreads();
  if (tid < 32) {
    float my = S.lam[tid];
    int rank = 0;
    for (int b = 0; b < 32; b++) {
      float ob = S.lam[b];
      rank += (ob > my) || (ob == my && b < tid);
    }
    S.ord[rank] = tid;
    S.lam2[rank] = my;
  }
  __syncthreads();
  if (tid == 0) {
    float tot = 0.f;
    for (int a = 0; a < 32; a++) tot += S.lam2[a];
    float cum = 0.f; int P = 0;
    for (int a = 0; a < 32; a++) { float rate = S.lam2[a] / tot; if (cum < 0.8f) P++; cum += rate; }
    S.Psh = P;
  }
  __syncthreads();
#pragma unroll
  for (int e = 0; e < 4; e++) {
    int i = i0 + 8 * e;
    S.Y[i][j256] = (j256 < S.Psh) ? S.V[i][S.ord[j256]] * sqrtf(fmaxf(S.lam2[j256], 0.f)) : 0.f;
  }
  __syncthreads();
  { int jj = tid >> 5, kk = tid & 31; S.C[jj][kk] = S.Y[jj][kk]; }
  if (tid < 32) S.asg[tid] = -1;
  __syncthreads();

  for (int it = 0; it <= 20; it++) {
    if (tid == 0) S.chg = 0;
    {
      int ii = tid >> 3, jj = tid & 7;
      float s = 0.f;
      for (int kk = 0; kk < 32; kk++) { float d = S.Y[ii][kk] - S.C[jj][kk]; s += d * d; }
      S.D[ii][jj] = s;
    }
    __syncthreads();
    if (tid < 32) {
      int best = 0; float bd = S.D[tid][0];
      for (int jj = 1; jj < 8; jj++) if (S.D[tid][jj] < bd) { bd = S.D[tid][jj]; best = jj; }
      if (best != S.asg[tid]) S.chg = 1;
      S.asg[tid] = best;
    }
    __syncthreads();
    if (it == 20 || S.chg == 0) break;  // chg==0: exact fixed point
    if (tid < 8) { int s = 0; for (int ii = 0; ii < 32; ii++) s += (S.asg[ii] == tid); S.cnt[tid] = s; }
    __syncthreads();
    {
      int jj = tid >> 5, kk = tid & 31;
      if (S.cnt[jj] > 0) {
        float s = 0.f;
        for (int ii = 0; ii < 32; ii++) if (S.asg[ii] == jj) s += S.Y[ii][kk];
        S.C[jj][kk] = s / (float)S.cnt[jj];
      }
    }
    __syncthreads();
  }
  if (tid < 32) r[tid] = S.asg[tid];
}

// f32 [E][K][N] tile -> bf16 [E][N][K] (transpose per expert), 64x64 tile
__device__ void wcvt_body(char* smem, const float* __restrict__ in, unsigned short* __restrict__ out,
                          int K, int N, int bx, int by, int e) {
  float (*T)[65] = reinterpret_cast<float(*)[65]>(smem);
  int tid = threadIdx.x;
  int tr = tid >> 4, tc = tid & 15;
  const float* ip = in + (size_t)e * K * N + (size_t)(by * 64) * N + bx * 64;
  unsigned short* op = out + (size_t)e * N * K + (size_t)(bx * 64) * K + by * 64;
#pragma unroll
  for (int rep = 0; rep < 4; rep++) {
    int row = rep * 16 + tr;
    float4 v = *(const float4*)(ip + (size_t)row * N + tc * 4);
    T[row][tc * 4 + 0] = v.x; T[row][tc * 4 + 1] = v.y;
    T[row][tc * 4 + 2] = v.z; T[row][tc * 4 + 3] = v.w;
  }
  __syncthreads();
#pragma unroll
  for (int rep = 0; rep < 4; rep++) {
    int nrow = rep * 16 + tr;
    float a = T[tc * 4 + 0][nrow], b = T[tc * 4 + 1][nrow];
    float c = T[tc * 4 + 2][nrow], d = T[tc * 4 + 3][nrow];
    uint2 wv; wv.x = packpair(a, b); wv.y = packpair(c, d);
    *(uint2*)(op + (size_t)nrow * K + tc * 4) = wv;
  }
}

// conversions + sent (blocks 19968..20063) — 20064 blocks
__global__ __launch_bounds__(256) void conv_kernel(
    const float* __restrict__ Wq, const float* __restrict__ Wk,
    const float* __restrict__ Wv, const float* __restrict__ Wo,
    const float* __restrict__ W1, const float* __restrict__ W2,
    unsigned short* __restrict__ Wqt, unsigned short* __restrict__ Wkt,
    unsigned short* __restrict__ Wvt, unsigned short* __restrict__ Wot,
    unsigned short* __restrict__ W1t, unsigned short* __restrict__ W2t,
    const float* __restrict__ hidden, unsigned short* __restrict__ xb,
    float* __restrict__ cbuf) {
  __shared__ __align__(16) char smem[17408];
  int b = blockIdx.x;
  if (b < 4608) {
    int which = b / 1152, sub = b % 1152;
    int bx = sub % 12, by = (sub / 12) % 12, e = sub / 144;
    const float* src = which == 0 ? Wq : which == 1 ? Wk : which == 2 ? Wv : Wo;
    unsigned short* dst = which == 0 ? Wqt : which == 1 ? Wkt : which == 2 ? Wvt : Wot;
    wcvt_body(smem, src, dst, Hn, Hn, bx, by, e);
  } else if (b < 9216) {
    int sub = b - 4608;
    int bx = sub % 48, by = (sub / 48) % 12, e = sub / 576;
    wcvt_body(smem, W1, W1t, Hn, INTERn, bx, by, e);
  } else if (b < 13824) {
    int sub = b - 9216;
    int bx = sub % 12, by = (sub / 12) % 48, e = sub / 576;
    wcvt_body(smem, W2, W2t, INTERn, Hn, bx, by, e);
  } else if (b < 19968) {
    int idx = (b - 13824) * 256 + threadIdx.x;
    const int n8 = (int)((size_t)Bn * Sn * Hn / 8);
    if (idx < n8) {
      const float* p = hidden + (size_t)idx * 8;
      float t[8];
      float4 a = *(const float4*)p, bb = *(const float4*)(p + 4);
      t[0] = a.x; t[1] = a.y; t[2] = a.z; t[3] = a.w;
      t[4] = bb.x; t[5] = bb.y; t[6] = bb.z; t[7] = bb.w;
      *(short8*)(xb + (size_t)idx * 8) = pack8(t);
    }
  } else {
    // sent: per-batch per-column mean of hidden (raw; route centers via Gram identity)
    int b2 = b - 19968;
    int batch = b2 & 31, part = b2 >> 5;
    int h = part * 256 + threadIdx.x;
    const float* p = hidden + (size_t)batch * Sn * Hn + h;
    float s = 0.f;
    for (int t = 0; t < Sn; t++) s += p[(size_t)t * Hn];
    cbuf[batch * Hn + h] = s * (1.f / (float)Sn);
  }
}

// ---------------- bf16 MFMA expert GEMM (m97 structure, BK=32 — verified r12) ----------------
// A bf16 [nbatch][512][lda]; Bt bf16 [E][N][K]; Y bf16 [nbatch][512][N].
// RES: 0 none, 1 f32 residual, 2 bf16 residual.
template <int ACT, int RES>
__global__ __launch_bounds__(256) void gemm_bt(
    const unsigned short* __restrict__ A, const unsigned short* __restrict__ Bt,
    const float* __restrict__ bias, const void* __restrict__ res,
    unsigned short* __restrict__ Y, const int* __restrict__ r,
    int K, int N, int lda, int bofs) {
  __shared__ __align__(16) unsigned short As[4096];  // 128 rows x 32 k
  __shared__ __align__(16) unsigned short Bs[4096];  // 128 cols x 32 k
  int z = blockIdx.z;
  int e = r[bofs + z];
  int tid = threadIdx.x;
  int wid = tid >> 6, lane = tid & 63;
  int wy = wid >> 1, wx = wid & 1;
  int lr = lane & 15, lg = lane >> 4;
  const unsigned short* Ab = A + (size_t)z * Sn * lda + (size_t)blockIdx.y * 128 * lda;
  const unsigned short* Bb = Bt + (size_t)e * N * K + (size_t)blockIdx.x * 128 * K;
  int r0 = wid * 16 + (lane >> 2);
  int r1 = (4 + wid) * 16 + (lane >> 2);
  int kk = (lane & 3) * 8;
  unsigned short* As0 = As + (size_t)wid * 512;
  unsigned short* As1 = As + (size_t)(4 + wid) * 512;
  unsigned short* Bs0 = Bs + (size_t)wid * 512;
  unsigned short* Bs1 = Bs + (size_t)(4 + wid) * 512;

  f32x4 acc[4][4];
#pragma unroll
  for (int m = 0; m < 4; m++)
#pragma unroll
    for (int n = 0; n < 4; n++) acc[m][n] = (f32x4){0.f, 0.f, 0.f, 0.f};

  for (int k0 = 0; k0 < K; k0 += 32) {
    gload16(Ab + (size_t)r0 * lda + k0 + kk, As0);
    gload16(Ab + (size_t)r1 * lda + k0 + kk, As1);
    gload16(Bb + (size_t)r0 * K + k0 + kk, Bs0);
    gload16(Bb + (size_t)r1 * K + k0 + kk, Bs1);
    __syncthreads();
    short8 af[4], bf[4];
#pragma unroll
    for (int m = 0; m < 4; m++) af[m] = *(const short8*)&As[(wy * 64 + m * 16 + lr) * 32 + lg * 8];
#pragma unroll
    for (int n = 0; n < 4; n++) bf[n] = *(const short8*)&Bs[(wx * 64 + n * 16 + lr) * 32 + lg * 8];
#pragma unroll
    for (int m = 0; m < 4; m++)
#pragma unroll
      for (int n = 0; n < 4; n++)
        acc[m][n] = __builtin_amdgcn_mfma_f32_16x16x32_bf16(af[m], bf[n], acc[m][n], 0, 0, 0);
    __syncthreads();
  }

  int row0 = blockIdx.y * 128 + wy * 64;
  int col0 = blockIdx.x * 128 + wx * 64;
#pragma unroll
  for (int m = 0; m < 4; m++) {
#pragma unroll
    for (int n = 0; n < 4; n++) {
      int col = col0 + n * 16 + lr;
      float bias_v = bias[e * N + col];
#pragma unroll
      for (int rr = 0; rr < 4; rr++) {
        int row = row0 + m * 16 + lg * 4 + rr;
        size_t off = ((size_t)z * Sn + row) * N + col;
        float v = acc[m][n][rr] + bias_v;
        if (RES == 1) v += ((const float*)res)[off];
        if (RES == 2) v += b2f(((const unsigned short*)res)[off]);
        if (ACT == 1) v = fast_gelu(v);
        Y[off] = f2b(v);
      }
    }
  }
}

// ---------------- 128x64-tile variant (for N-narrow GEMMs like W2: doubles block count) ----------------
// Same fragment math/accumulation order as gemm_bt -> bit-identical outputs.
template <int ACT, int RES>
__global__ __launch_bounds__(256) void gemm_bt64(
    const unsigned short* __restrict__ A, const unsigned short* __restrict__ Bt,
    const float* __restrict__ bias, const void* __restrict__ res,
    unsigned short* __restrict__ Y, const int* __restrict__ r,
    int K, int N, int lda, int bofs) {
  __shared__ __align__(16) unsigned short As[4096];  // 128 rows x 32 k
  __shared__ __align__(16) unsigned short Bs[2048];  // 64 cols x 32 k
  int z = blockIdx.z;
  int e = r[bofs + z];
  int tid = threadIdx.x;
  int wid = tid >> 6, lane = tid & 63;
  int wy = wid >> 1, wx = wid & 1;           // wave sub-tile: 64 rows x 32 cols
  int lr = lane & 15, lg = lane >> 4;
  const unsigned short* Ab = A + (size_t)z * Sn * lda + (size_t)blockIdx.y * 128 * lda;
  const unsigned short* Bb = Bt + (size_t)e * N * K + (size_t)blockIdx.x * 64 * K;
  int r0 = wid * 16 + (lane >> 2);           // 0..63 across wids
  int r1 = (4 + wid) * 16 + (lane >> 2);     // 64..127
  int kk = (lane & 3) * 8;
  unsigned short* As0 = As + (size_t)wid * 512;
  unsigned short* As1 = As + (size_t)(4 + wid) * 512;
  unsigned short* Bs0 = Bs + (size_t)wid * 512;   // rows 0..63 only

  f32x4 acc[4][2];
#pragma unroll
  for (int m = 0; m < 4; m++)
#pragma unroll
    for (int n = 0; n < 2; n++) acc[m][n] = (f32x4){0.f, 0.f, 0.f, 0.f};

  for (int k0 = 0; k0 < K; k0 += 32) {
    gload16(Ab + (size_t)r0 * lda + k0 + kk, As0);
    gload16(Ab + (size_t)r1 * lda + k0 + kk, As1);
    gload16(Bb + (size_t)r0 * K + k0 + kk, Bs0);
    __syncthreads();
    short8 af[4], bf[2];
#pragma unroll
    for (int m = 0; m < 4; m++) af[m] = *(const short8*)&As[(wy * 64 + m * 16 + lr) * 32 + lg * 8];
#pragma unroll
    for (int n = 0; n < 2; n++) bf[n] = *(const short8*)&Bs[(wx * 32 + n * 16 + lr) * 32 + lg * 8];
#pragma unroll
    for (int m = 0; m < 4; m++)
#pragma unroll
      for (int n = 0; n < 2; n++)
        acc[m][n] = __builtin_amdgcn_mfma_f32_16x16x32_bf16(af[m], bf[n], acc[m][n], 0, 0, 0);
    __syncthreads();
  }

  int row0 = blockIdx.y * 128 + wy * 64;
  int col0 = blockIdx.x * 64 + wx * 32;
#pragma unroll
  for (int m = 0; m < 4; m++) {
#pragma unroll
    for (int n = 0; n < 2; n++) {
      int col = col0 + n * 16 + lr;
      float bias_v = bias[e * N + col];
#pragma unroll
      for (int rr = 0; rr < 4; rr++) {
        int row = row0 + m * 16 + lg * 4 + rr;
        size_t off = ((size_t)z * Sn + row) * N + col;
        float v = acc[m][n][rr] + bias_v;
        if (RES == 1) v += ((const float*)res)[off];
        if (RES == 2) v += b2f(((const unsigned short*)res)[off]);
        if (ACT == 1) v = fast_gelu(v);
        Y[off] = f2b(v);
      }
    }
  }
}

// fused Q/K/V projection (BK=32): grid.z = 96, which = z>>5, batch = z&31
__global__ __launch_bounds__(256) void gemm_qkv(
    const unsigned short* __restrict__ A,
    const unsigned short* __restrict__ Wq, const unsigned short* __restrict__ Wk,
    const unsigned short* __restrict__ Wv,
    const float* __restrict__ bq, const float* __restrict__ bk, const float* __restrict__ bv,
    unsigned short* __restrict__ Oq, unsigned short* __restrict__ Ok, unsigned short* __restrict__ Ov,
    const int* __restrict__ r) {
  __shared__ __align__(16) unsigned short As[4096];
  __shared__ __align__(16) unsigned short Bs[4096];
  const int K = Hn, N = Hn, lda = Hn;
  int zz = blockIdx.z;
  int which = zz >> 5, z = zz & 31;
  const unsigned short* Bt = which == 0 ? Wq : which == 1 ? Wk : Wv;
  const float* bias = which == 0 ? bq : which == 1 ? bk : bv;
  unsigned short* Y = which == 0 ? Oq : which == 1 ? Ok : Ov;
  int e = r[z];
  int tid = threadIdx.x;
  int wid = tid >> 6, lane = tid & 63;
  int wy = wid >> 1, wx = wid & 1;
  int lr = lane & 15, lg = lane >> 4;
  const unsigned short* Ab = A + (size_t)z * Sn * lda + (size_t)blockIdx.y * 128 * lda;
  const unsigned short* Bb = Bt + (size_t)e * N * K + (size_t)blockIdx.x * 128 * K;
  int r0 = wid * 16 + (lane >> 2);
  int r1 = (4 + wid) * 16 + (lane >> 2);
  int kk = (lane & 3) * 8;
  unsigned short* As0 = As + (size_t)wid * 512;
  unsigned short* As1 = As + (size_t)(4 + wid) * 512;
  unsigned short* Bs0 = Bs + (size_t)wid * 512;
  unsigned short* Bs1 = Bs + (size_t)(4 + wid) * 512;

  f32x4 acc[4][4];
#pragma unroll
  for (int m = 0; m < 4; m++)
#pragma unroll
    for (int n = 0; n < 4; n++) acc[m][n] = (f32x4){0.f, 0.f, 0.f, 0.f};

  for (int k0 = 0; k0 < K; k0 += 32) {
    gload16(Ab + (size_t)r0 * lda + k0 + kk, As0);
    gload16(Ab + (size_t)r1 * lda + k0 + kk, As1);
    gload16(Bb + (size_t)r0 * K + k0 + kk, Bs0);
    gload16(Bb + (size_t)r1 * K + k0 + kk, Bs1);
    __syncthreads();
    short8 af[4], bf[4];
#pragma unroll
    for (int m = 0; m < 4; m++) af[m] = *(const short8*)&As[(wy * 64 + m * 16 + lr) * 32 + lg * 8];
#pragma unroll
    for (int n = 0; n < 4; n++) bf[n] = *(const short8*)&Bs[(wx * 64 + n * 16 + lr) * 32 + lg * 8];
#pragma unroll
    for (int m = 0; m < 4; m++)
#pragma unroll
      for (int n = 0; n < 4; n++)
        acc[m][n] = __builtin_amdgcn_mfma_f32_16x16x32_bf16(af[m], bf[n], acc[m][n], 0, 0, 0);
    __syncthreads();
  }

  int row0 = blockIdx.y * 128 + wy * 64;
  int col0 = blockIdx.x * 128 + wx * 64;
#pragma unroll
  for (int m = 0; m < 4; m++) {
#pragma unroll
    for (int n = 0; n < 4; n++) {
      int col = col0 + n * 16 + lr;
      float bias_v = bias[e * N + col];
#pragma unroll
      for (int rr = 0; rr < 4; rr++) {
        int row = row0 + m * 16 + lg * 4 + rr;
        size_t off = ((size_t)z * Sn + row) * N + col;
        Y[off] = f2b(acc[m][n][rr] + bias_v);
      }
    }
  }
}

// ---------------- MFMA flash attention (bf16 in/out), KVBLK=64 ----------------
__global__ __launch_bounds__(256) void attn_mfma(
    const unsigned short* qb, const unsigned short* __restrict__ kb,
    const unsigned short* __restrict__ vb, const float* __restrict__ amask,
    unsigned short* ctx) {
  __shared__ short Kl[64][72];
  __shared__ short Vt[64][72];
  __shared__ float mk[512];
  int qt = blockIdx.x, h = blockIdx.y, b = blockIdx.z;
  int tid = threadIdx.x, w = tid >> 6, lane = tid & 63;
  int lr = lane & 15, lg = lane >> 4;

  for (int i2 = tid; i2 < 512; i2 += 256) mk[i2] = (1.f - amask[b * Sn + i2]) * (-10000.f);

  int qrow = qt * 64 + w * 16 + lr;
  const unsigned short* qp = qb + ((size_t)(b * Sn + qrow)) * Hn + h * 64 + lg * 8;
  short8 qf0 = *(const short8*)qp;
  short8 qf1 = *(const short8*)(qp + 32);

  f32x4 o[4];
#pragma unroll
  for (int f = 0; f < 4; f++) o[f] = (f32x4){0.f, 0.f, 0.f, 0.f};
  float mrun = -3e38f, lsum = 0.f;

  for (int kv0 = 0; kv0 < Sn; kv0 += 64) {
    __syncthreads();
    {  // K tile [64][64] bf16: each thread loads 2 rows
      int kvr = tid >> 3, i8 = tid & 7;
      const unsigned short* kp = kb + ((size_t)(b * Sn + kv0 + kvr)) * Hn + h * 64 + i8 * 8;
      *(short8*)&Kl[kvr][i8 * 8] = *(const short8*)kp;
      *(short8*)&Kl[kvr + 32][i8 * 8] = *(const short8*)(kp + (size_t)32 * Hn);
    }
    {  // V^T tile [64 d][64 kv]: each thread packs 2 groups of 8 kv
      int d = tid & 63, kq = tid >> 6;
#pragma unroll
      for (int gq = 0; gq < 2; gq++) {
        int kvg = kq + gq * 4;
        const unsigned short* vp = vb + ((size_t)(b * Sn + kv0 + kvg * 8)) * Hn + h * 64 + d;
        unsigned a0 = (unsigned)vp[0] | ((unsigned)vp[Hn] << 16);
        unsigned a1 = (unsigned)vp[2 * Hn] | ((unsigned)vp[3 * Hn] << 16);
        unsigned a2 = (unsigned)vp[4 * Hn] | ((unsigned)vp[5 * Hn] << 16);
        unsigned a3 = (unsigned)vp[6 * Hn] | ((unsigned)vp[7 * Hn] << 16);
        int4v wv; wv.x = (int)a0; wv.y = (int)a1; wv.z = (int)a2; wv.w = (int)a3;
        *(short8*)&Vt[d][kvg * 8] = __builtin_bit_cast(short8, wv);
      }
    }
    __syncthreads();

    f32x4 s[4];
#pragma unroll
    for (int qq = 0; qq < 4; qq++) {
      s[qq] = (f32x4){0.f, 0.f, 0.f, 0.f};
      short8 ka = *(short8*)&Kl[qq * 16 + lr][lg * 8];
      short8 kc = *(short8*)&Kl[qq * 16 + lr][32 + lg * 8];
      s[qq] = __builtin_amdgcn_mfma_f32_16x16x32_bf16(ka, qf0, s[qq], 0, 0, 0);
      s[qq] = __builtin_amdgcn_mfma_f32_16x16x32_bf16(kc, qf1, s[qq], 0, 0, 0);
    }
#pragma unroll
    for (int qq = 0; qq < 4; qq++) {
      f32x4 mq = *(f32x4*)&mk[kv0 + qq * 16 + lg * 4];
#pragma unroll
      for (int rr = 0; rr < 4; rr++) s[qq][rr] = s[qq][rr] * 0.125f + mq[rr];
    }

    float pm = -1e30f;
#pragma unroll
    for (int qq = 0; qq < 4; qq++)
#pragma unroll
      for (int rr = 0; rr < 4; rr++) pm = fmaxf(pm, s[qq][rr]);
    pm = fmaxf(pm, __shfl_xor(pm, 16, 64));
    pm = fmaxf(pm, __shfl_xor(pm, 32, 64));
    float mn = fmaxf(mrun, pm);
    float al = __expf(mrun - mn);
    float p0[4], p1[4], p2[4], p3[4];
    float ls = 0.f;
#pragma unroll
    for (int rr = 0; rr < 4; rr++) { p0[rr] = __expf(s[0][rr] - mn); ls += p0[rr]; }
#pragma unroll
    for (int rr = 0; rr < 4; rr++) { p1[rr] = __expf(s[1][rr] - mn); ls += p1[rr]; }
#pragma unroll
    for (int rr = 0; rr < 4; rr++) { p2[rr] = __expf(s[2][rr] - mn); ls += p2[rr]; }
#pragma unroll
    for (int rr = 0; rr < 4; rr++) { p3[rr] = __expf(s[3][rr] - mn); ls += p3[rr]; }
    ls += __shfl_xor(ls, 16, 64);
    ls += __shfl_xor(ls, 32, 64);
    lsum = lsum * al + ls;
    mrun = mn;
#pragma unroll
    for (int f = 0; f < 4; f++)
#pragma unroll
      for (int rr = 0; rr < 4; rr++) o[f][rr] *= al;

    int srcA = lr + (((2 * lg) & 3) << 4);
    int srcB = srcA + 16;
    bool lo = lg < 2;
    short8 pf0, pf1;
    {
      unsigned a0p = packpair(p0[0], p0[1]), a1p = packpair(p0[2], p0[3]);
      unsigned b0p = packpair(p1[0], p1[1]), b1p = packpair(p1[2], p1[3]);
      unsigned xa0 = __shfl(a0p, srcA, 64), xa1 = __shfl(a1p, srcA, 64);
      unsigned xb0 = __shfl(b0p, srcA, 64), xb1 = __shfl(b1p, srcA, 64);
      unsigned ya0 = __shfl(a0p, srcB, 64), ya1 = __shfl(a1p, srcB, 64);
      unsigned yb0 = __shfl(b0p, srcB, 64), yb1 = __shfl(b1p, srcB, 64);
      int4v pw;
      pw.x = (int)(lo ? xa0 : xb0); pw.y = (int)(lo ? xa1 : xb1);
      pw.z = (int)(lo ? ya0 : yb0); pw.w = (int)(lo ? ya1 : yb1);
      pf0 = __builtin_bit_cast(short8, pw);
    }
    {
      unsigned a0p = packpair(p2[0], p2[1]), a1p = packpair(p2[2], p2[3]);
      unsigned b0p = packpair(p3[0], p3[1]), b1p = packpair(p3[2], p3[3]);
      unsigned xa0 = __shfl(a0p, srcA, 64), xa1 = __shfl(a1p, srcA, 64);
      unsigned xb0 = __shfl(b0p, srcA, 64), xb1 = __shfl(b1p, srcA, 64);
      unsigned ya0 = __shfl(a0p, srcB, 64), ya1 = __shfl(a1p, srcB, 64);
      unsigned yb0 = __shfl(b0p, srcB, 64), yb1 = __shfl(b1p, srcB, 64);
      int4v pw;
      pw.x = (int)(lo ? xa0 : xb0); pw.y = (int)(lo ? xa1 : xb1);
      pw.z = (int)(lo ? ya0 : yb0); pw.w = (int)(lo ? ya1 : yb1);
      pf1 = __builtin_bit_cast(short8, pw);
    }

#pragma unroll
    for (int f = 0; f < 4; f++) {
      short8 vf0 = *(short8*)&Vt[f * 16 + lr][lg * 8];
      short8 vf1 = *(short8*)&Vt[f * 16 + lr][32 + lg * 8];
      o[f] = __builtin_amdgcn_mfma_f32_16x16x32_bf16(vf0, pf0, o[f], 0, 0, 0);
      o[f] = __builtin_amdgcn_mfma_f32_16x16x32_bf16(vf1, pf1, o[f], 0, 0, 0);
    }
  }

  float inv = 1.f / lsum;
  unsigned short* op = ctx + ((size_t)(b * Sn + qt * 64 + w * 16 + lr)) * Hn + h * 64;
#pragma unroll
  for (int f = 0; f < 4; f++) {
    uint2 wv;
    wv.x = packpair(o[f][0] * inv, o[f][1] * inv);
    wv.y = packpair(o[f][2] * inv, o[f][3] * inv);
    *(uint2*)(op + f * 16 + lg * 4) = wv;
  }
}

// ---------------- layernorm (bf16 in; bf16 or f32 out) ----------------
template <int OUTF32>
__global__ __launch_bounds__(256) void ln_bf(const unsigned short* __restrict__ X, void* __restrict__ Yv,
    const float* __restrict__ gam, const float* __restrict__ bet, const int* __restrict__ r) {
  __shared__ float red1[4], red2[4];
  int row = blockIdx.x;
  int tid = threadIdx.x;
  const unsigned short* x = X + (size_t)row * Hn;
  float v0 = b2f(x[tid]), v1 = b2f(x[tid + 256]), v2 = b2f(x[tid + 512]);
  float s = v0 + v1 + v2;
#pragma unroll
  for (int o = 32; o; o >>= 1) s += __shfl_xor(s, o, 64);
  if ((tid & 63) == 0) red1[tid >> 6] = s;
  __syncthreads();
  float mu = (red1[0] + red1[1] + red1[2] + red1[3]) * (1.f / (float)Hn);
  float d0 = v0 - mu, d1 = v1 - mu, d2 = v2 - mu;
  float q = d0 * d0 + d1 * d1 + d2 * d2;
#pragma unroll
  for (int o = 32; o; o >>= 1) q += __shfl_xor(q, o, 64);
  if ((tid & 63) == 0) red2[tid >> 6] = q;
  __syncthreads();
  float var = (red2[0] + red2[1] + red2[2] + red2[3]) * (1.f / (float)Hn);
  float inv = rsqrtf(var + 1e-12f);
  int e = r[row >> 9];
  const float* g = gam + e * Hn;
  const float* be = bet + e * Hn;
  float o0 = d0 * inv * g[tid] + be[tid];
  float o1 = d1 * inv * g[tid + 256] + be[tid + 256];
  float o2 = d2 * inv * g[tid + 512] + be[tid + 512];
  if (OUTF32) {
    float* y = (float*)Yv + (size_t)row * Hn;
    y[tid] = o0; y[tid + 256] = o1; y[tid + 512] = o2;
  } else {
    unsigned short* y = (unsigned short*)Yv + (size_t)row * Hn;
    y[tid] = f2b(o0); y[tid + 256] = f2b(o1); y[tid + 512] = f2b(o2);
  }
}

// ---------------- launch ----------------
extern "C" void kernel_launch(void* const* d_in, const int* in_sizes, int n_in,
                              void* d_out, int out_size, void* d_ws, size_t ws_size,
                              hipStream_t stream) {
  const float* hidden = (const float*)d_in[0];
  const float* amask  = (const float*)d_in[1];
  const float* Wq = (const float*)d_in[2];
  const float* bq = (const float*)d_in[3];
  const float* Wk = (const float*)d_in[4];
  const float* bk = (const float*)d_in[5];
  const float* Wv = (const float*)d_in[6];
  const float* bv = (const float*)d_in[7];
  const float* Wo = (const float*)d_in[8];
  const float* bo = (const float*)d_in[9];
  const float* g1 = (const float*)d_in[10];
  const float* b1g = (const float*)d_in[11];
  const float* W1 = (const float*)d_in[12];
  const float* b1 = (const float*)d_in[13];
  const float* W2 = (const float*)d_in[14];
  const float* b2 = (const float*)d_in[15];
  const float* g2 = (const float*)d_in[16];
  const float* b2g = (const float*)d_in[17];
  float* out = (float*)d_out;

  char* w = (char*)d_ws;
  int* r = (int*)w;                              // 128 B
  float* cbuf = (float*)(w + 8192);              // 96 KB (raw sent means)
  const size_t TOK = (size_t)Bn * Sn;            // 16384
  size_t off = (size_t)1 << 20;
  const size_t WSML = (size_t)En * Hn * Hn * 2;        // 9.4 MB
  const size_t WBIG = (size_t)En * Hn * INTERn * 2;    // 37.7 MB
  const size_t ABUF = TOK * Hn * 2;                    // 25.2 MB
  unsigned short* Wqt = (unsigned short*)(w + off); off += WSML;
  unsigned short* Wkt = (unsigned short*)(w + off); off += WSML;
  unsigned short* Wvt = (unsigned short*)(w + off); off += WSML;
  unsigned short* Wot = (unsigned short*)(w + off); off += WSML;
  unsigned short* W1t = (unsigned short*)(w + off); off += WBIG;
  unsigned short* W2t = (unsigned short*)(w + off); off += WBIG;
  unsigned short* xb  = (unsigned short*)(w + off); off += ABUF;  // x_bf -> att_bf
  unsigned short* qb2 = (unsigned short*)(w + off); off += ABUF;  // q -> ctx
  unsigned short* kb2 = (unsigned short*)(w + off); off += ABUF;  // k -> ffn_pre
  unsigned short* vb2 = (unsigned short*)(w + off); off += ABUF;  // v -> h1 chunk (with pb)
  unsigned short* pb  = (unsigned short*)(w + off); off += ABUF;  // att_pre; part of h1 chunk
  // total ~229 MB. vb2+pb adjacent = 50 MB = h1 chunk for G=16.

  // conversions + sent (independent) — one wide kernel
  conv_kernel<<<20064, 256, 0, stream>>>(Wq, Wk, Wv, Wo, W1, W2,
                                         Wqt, Wkt, Wvt, Wot, W1t, W2t, hidden, xb, cbuf);

  // routing: raw-Gram centering inside route (no center kernel)
  route_kernel<<<1, 256, 0, stream>>>(cbuf, r);

  // fused q,k,v projections
  gemm_qkv<<<dim3(6, 4, 96), 256, 0, stream>>>(xb, Wqt, Wkt, Wvt, bq, bk, bv, qb2, kb2, vb2, r);

  // attention (ctx in-place over qb2)
  attn_mfma<<<dim3(8, 12, 32), 256, 0, stream>>>(qb2, kb2, vb2, amask, qb2);

  // output projection + f32 residual(hidden) -> pb (att_pre bf16); LN1 -> xb (att_bf)
  gemm_bt<0, 1><<<dim3(6, 4, 32), 256, 0, stream>>>(qb2, Wot, bo, hidden, pb, r, Hn, Hn, Hn, 0);
  ln_bf<0><<<16384, 256, 0, stream>>>(pb, xb, g1, b1g, r);

  // FFN chunked G=16: h1 chunk spans vb2+pb (both dead); ffn_pre -> kb2
  // W2 uses the 128x64-tile variant (N=768 -> 12 N-tiles, 768 blocks = 3/CU vs 1.5/CU)
  const int G = 16;
  unsigned short* h1c = vb2;  // 50 MB region (vb2..pb end)
  for (int c = 0; c < Bn / G; c++) {
    const unsigned short* attc = xb + (size_t)c * G * Sn * Hn;
    unsigned short* ffc = kb2 + (size_t)c * G * Sn * Hn;
    gemm_bt<1, 0><<<dim3(24, 4, G), 256, 0, stream>>>(attc, W1t, b1, nullptr, h1c, r, Hn, INTERn, Hn, c * G);
    gemm_bt64<0, 2><<<dim3(12, 4, G), 256, 0, stream>>>(h1c, W2t, b2, attc, ffc, r, INTERn, Hn, INTERn, c * G);
  }
  ln_bf<1><<<16384, 256, 0, stream>>>(kb2, out, g2, b2g, r);
}

// Round 29
// 788.369 us; speedup vs baseline: 1.1295x; 1.1295x over previous
//
#include <hip/hip_runtime.h>
#include <math.h>

constexpr int Bn = 32, Sn = 512, Hn = 768, NHn = 12, DHn = 64, INTERn = 3072, En = 8;

typedef __attribute__((ext_vector_type(4))) float f32x4;
typedef __attribute__((ext_vector_type(8))) short short8;
typedef __attribute__((ext_vector_type(4))) int int4v;

__device__ inline unsigned short f2b(float x) {
  unsigned u = __builtin_bit_cast(unsigned, x);
  return (unsigned short)((u + 0x7fffu + ((u >> 16) & 1u)) >> 16);
}
__device__ inline float b2f(unsigned short u) {
  unsigned x = ((unsigned)u) << 16;
  return __builtin_bit_cast(float, x);
}
__device__ inline unsigned packpair(float a, float b) {
  return (unsigned)f2b(a) | ((unsigned)f2b(b) << 16);
}
__device__ inline short8 pack8(const float* p) {
  int4v w;
  w.x = (int)packpair(p[0], p[1]); w.y = (int)packpair(p[2], p[3]);
  w.z = (int)packpair(p[4], p[5]); w.w = (int)packpair(p[6], p[7]);
  return __builtin_bit_cast(short8, w);
}
__device__ inline float fast_gelu(float u) {
  float z = 0.7978845608028654f * (u + 0.044715f * u * u * u);
  float e = __expf(2.f * z);
  float t = 1.f - 2.f / (e + 1.f);
  return 0.5f * u * (1.f + t);
}
// async global->LDS, 16B per lane; lds base must be wave-uniform (HW adds lane*16)
__device__ inline void gload16(const void* g, void* l) {
  __builtin_amdgcn_global_load_lds(
      (const __attribute__((address_space(1))) unsigned int*)g,
      (__attribute__((address_space(3))) unsigned int*)l, 16, 0, 0);
}

// ---------------- standalone route: raw-gram + centering + 3-sweep Jacobi + kmeans(early-exit) ----------------
// (3 sweeps = verified routing floor — r20. 4-wave barriers = floor structure — r25 (1-wave serial: 193us).
//  r26/r27 VERIFIED FLOOR: fused two-sided update, 3 barriers/round, 138.5us.
//  r28 per-thread redundant rotations REGRESSED (240us: divergent LDS reads 4.5x bank conflicts
//  + 5x serial sqrt/div chains). This is the measured optimum of the route design space.)

struct RouteSM {
  float A[32][33];
  float V[32][33];
  float csA[32], snA[32];
  int partner[32], isP[32];
  float Y[32][32];
  float C[8][32];
  float D[32][8];
  float lam[32];
  float lam2[32];
  float rs[32];
  float gsum;
  int ord[32];
  int asg[32];
  int cnt[8];
  int Psh;
  int chg;
};

__global__ __launch_bounds__(256) void route_kernel(const float* __restrict__ cbuf, int* __restrict__ r) {
  __shared__ __align__(16) char smem[24576];
  RouteSM& S = *reinterpret_cast<RouteSM*>(smem);
  int tid = threadIdx.x;
  int i0 = tid >> 5, j256 = tid & 31;

  // ---- raw Gram (256 threads): A[i][j] = dot(raw_i, raw_j) ----
  {
    float s[4] = {0.f, 0.f, 0.f, 0.f};
    const float* cj = cbuf + (size_t)j256 * Hn;
    for (int t = 0; t < Hn; t += 4) {
      float4 y = *(const float4*)(cj + t);
#pragma unroll
      for (int e = 0; e < 4; e++) {
        const float* ci = cbuf + (size_t)(i0 + 8 * e) * Hn;
        float4 x = *(const float4*)(ci + t);
        s[e] += x.x * y.x + x.y * y.y + x.z * y.z + x.w * y.w;
      }
    }
#pragma unroll
    for (int e = 0; e < 4; e++) {
      int i = i0 + 8 * e;
      S.A[i][j256] = s[e];
      S.V[i][j256] = (i == j256) ? 1.f : 0.f;
    }
  }
  __syncthreads();
  // ---- center the Gram: Gc = G - (rs_i + rs_j)/32 + gs/1024 (exact identity) ----
  if (tid < 32) {
    float s = 0.f;
    for (int jj = 0; jj < 32; jj++) s += S.A[tid][jj];
    S.rs[tid] = s;
  }
  __syncthreads();
  if (tid == 0) {
    float g = 0.f;
    for (int a = 0; a < 32; a++) g += S.rs[a];
    S.gsum = g * (1.f / 1024.f);
  }
  __syncthreads();
  {
    float corr = S.gsum;
#pragma unroll
    for (int e = 0; e < 4; e++) {
      int i = i0 + 8 * e;
      S.A[i][j256] = S.A[i][j256] - (S.rs[i] + S.rs[j256]) * (1.f / 32.f) + corr;
    }
  }
  __syncthreads();

  // ---- Jacobi: fixed 3 sweeps, fused two-sided update (3 barriers/round) ----
  for (int sweep = 0; sweep < 3; sweep++) {
    for (int rnd = 0; rnd < 31; rnd++) {
      if (tid < 16) {
        int p, q;
        if (tid == 0) { p = rnd % 31; q = 31; }
        else { p = (rnd + tid) % 31; q = (rnd + 31 - tid) % 31; }
        float app = S.A[p][p], aqq = S.A[q][q], apq = S.A[p][q];
        float cc = 1.f, ss = 0.f;
        if (fabsf(apq) > 1e-18f) {
          float tau = (aqq - app) / (2.f * apq);
          float t = 1.f / (fabsf(tau) + sqrtf(1.f + tau * tau));
          if (tau < 0.f) t = -t;
          cc = 1.f / sqrtf(1.f + t * t);
          ss = t * cc;
        }
        S.partner[p] = q; S.partner[q] = p; S.isP[p] = 1; S.isP[q] = 0;
        S.csA[p] = cc; S.csA[q] = cc; S.snA[p] = ss; S.snA[q] = ss;
      }
      __syncthreads();
      float nb[4], nv[4];
      {
        int pj = S.partner[j256]; float cc = S.csA[j256], ss = S.snA[j256]; int ipj = S.isP[j256];
#pragma unroll
        for (int e = 0; e < 4; e++) {
          int i = i0 + 8 * e;
          // col update of own row (== old phase-2 na for (i,j)):
          float a = S.A[i][j256], a2 = S.A[i][pj];
          float t1 = ipj ? (cc * a - ss * a2) : (ss * a2 + cc * a);
          float v1 = S.V[i][j256], v2 = S.V[i][pj];
          nv[e] = ipj ? (cc * v1 - ss * v2) : (ss * v2 + cc * v1);
          // col update of partner row (== old phase-2 na for (pi,j)):
          int pi2 = S.partner[i]; float c2 = S.csA[i], s2 = S.snA[i]; int ipi = S.isP[i];
          float b = S.A[pi2][j256], b2 = S.A[pi2][pj];
          float t2 = ipj ? (cc * b - ss * b2) : (ss * b2 + cc * b);
          // row update (== old phase-4 nb):
          nb[e] = ipi ? (c2 * t1 - s2 * t2) : (s2 * t2 + c2 * t1);
        }
      }
      __syncthreads();
#pragma unroll
      for (int e = 0; e < 4; e++) { int i = i0 + 8 * e; S.A[i][j256] = nb[e]; S.V[i][j256] = nv[e]; }
      __syncthreads();
    }
  }

  // ---- sort / keep-rule / k-means (verified; early-exit is exact) ----
  if (tid < 32) S.lam[tid] = S.A[tid][tid];
  __syncthreads();
  if (tid < 32) {
    float my = S.lam[tid];
    int rank = 0;
    for (int b = 0; b < 32; b++) {
      float ob = S.lam[b];
      rank += (ob > my) || (ob == my && b < tid);
    }
    S.ord[rank] = tid;
    S.lam2[rank] = my;
  }
  __syncthreads();
  if (tid == 0) {
    float tot = 0.f;
    for (int a = 0; a < 32; a++) tot += S.lam2[a];
    float cum = 0.f; int P = 0;
    for (int a = 0; a < 32; a++) { float rate = S.lam2[a] / tot; if (cum < 0.8f) P++; cum += rate; }
    S.Psh = P;
  }
  __syncthreads();
#pragma unroll
  for (int e = 0; e < 4; e++) {
    int i = i0 + 8 * e;
    S.Y[i][j256] = (j256 < S.Psh) ? S.V[i][S.ord[j256]] * sqrtf(fmaxf(S.lam2[j256], 0.f)) : 0.f;
  }
  __syncthreads();
  { int jj = tid >> 5, kk = tid & 31; S.C[jj][kk] = S.Y[jj][kk]; }
  if (tid < 32) S.asg[tid] = -1;
  __syncthreads();

  for (int it = 0; it <= 20; it++) {
    if (tid == 0) S.chg = 0;
    {
      int ii = tid >> 3, jj = tid & 7;
      float s = 0.f;
      for (int kk = 0; kk < 32; kk++) { float d = S.Y[ii][kk] - S.C[jj][kk]; s += d * d; }
      S.D[ii][jj] = s;
    }
    __syncthreads();
    if (tid < 32) {
      int best = 0; float bd = S.D[tid][0];
      for (int jj = 1; jj < 8; jj++) if (S.D[tid][jj] < bd) { bd = S.D[tid][jj]; best = jj; }
      if (best != S.asg[tid]) S.chg = 1;
      S.asg[tid] = best;
    }
    __syncthreads();
    if (it == 20 || S.chg == 0) break;  // chg==0: exact fixed point
    if (tid < 8) { int s = 0; for (int ii = 0; ii < 32; ii++) s += (S.asg[ii] == tid); S.cnt[tid] = s; }
    __syncthreads();
    {
      int jj = tid >> 5, kk = tid & 31;
      if (S.cnt[jj] > 0) {
        float s = 0.f;
        for (int ii = 0; ii < 32; ii++) if (S.asg[ii] == jj) s += S.Y[ii][kk];
        S.C[jj][kk] = s / (float)S.cnt[jj];
      }
    }
    __syncthreads();
  }
  if (tid < 32) r[tid] = S.asg[tid];
}

// f32 [E][K][N] tile -> bf16 [E][N][K] (transpose per expert), 64x64 tile
__device__ void wcvt_body(char* smem, const float* __restrict__ in, unsigned short* __restrict__ out,
                          int K, int N, int bx, int by, int e) {
  float (*T)[65] = reinterpret_cast<float(*)[65]>(smem);
  int tid = threadIdx.x;
  int tr = tid >> 4, tc = tid & 15;
  const float* ip = in + (size_t)e * K * N + (size_t)(by * 64) * N + bx * 64;
  unsigned short* op = out + (size_t)e * N * K + (size_t)(bx * 64) * K + by * 64;
#pragma unroll
  for (int rep = 0; rep < 4; rep++) {
    int row = rep * 16 + tr;
    float4 v = *(const float4*)(ip + (size_t)row * N + tc * 4);
    T[row][tc * 4 + 0] = v.x; T[row][tc * 4 + 1] = v.y;
    T[row][tc * 4 + 2] = v.z; T[row][tc * 4 + 3] = v.w;
  }
  __syncthreads();
#pragma unroll
  for (int rep = 0; rep < 4; rep++) {
    int nrow = rep * 16 + tr;
    float a = T[tc * 4 + 0][nrow], b = T[tc * 4 + 1][nrow];
    float c = T[tc * 4 + 2][nrow], d = T[tc * 4 + 3][nrow];
    uint2 wv; wv.x = packpair(a, b); wv.y = packpair(c, d);
    *(uint2*)(op + (size_t)nrow * K + tc * 4) = wv;
  }
}

// conversions + sent (blocks 19968..20063) — 20064 blocks
__global__ __launch_bounds__(256) void conv_kernel(
    const float* __restrict__ Wq, const float* __restrict__ Wk,
    const float* __restrict__ Wv, const float* __restrict__ Wo,
    const float* __restrict__ W1, const float* __restrict__ W2,
    unsigned short* __restrict__ Wqt, unsigned short* __restrict__ Wkt,
    unsigned short* __restrict__ Wvt, unsigned short* __restrict__ Wot,
    unsigned short* __restrict__ W1t, unsigned short* __restrict__ W2t,
    const float* __restrict__ hidden, unsigned short* __restrict__ xb,
    float* __restrict__ cbuf) {
  __shared__ __align__(16) char smem[17408];
  int b = blockIdx.x;
  if (b < 4608) {
    int which = b / 1152, sub = b % 1152;
    int bx = sub % 12, by = (sub / 12) % 12, e = sub / 144;
    const float* src = which == 0 ? Wq : which == 1 ? Wk : which == 2 ? Wv : Wo;
    unsigned short* dst = which == 0 ? Wqt : which == 1 ? Wkt : which == 2 ? Wvt : Wot;
    wcvt_body(smem, src, dst, Hn, Hn, bx, by, e);
  } else if (b < 9216) {
    int sub = b - 4608;
    int bx = sub % 48, by = (sub / 48) % 12, e = sub / 576;
    wcvt_body(smem, W1, W1t, Hn, INTERn, bx, by, e);
  } else if (b < 13824) {
    int sub = b - 9216;
    int bx = sub % 12, by = (sub / 12) % 48, e = sub / 576;
    wcvt_body(smem, W2, W2t, INTERn, Hn, bx, by, e);
  } else if (b < 19968) {
    int idx = (b - 13824) * 256 + threadIdx.x;
    const int n8 = (int)((size_t)Bn * Sn * Hn / 8);
    if (idx < n8) {
      const float* p = hidden + (size_t)idx * 8;
      float t[8];
      float4 a = *(const float4*)p, bb = *(const float4*)(p + 4);
      t[0] = a.x; t[1] = a.y; t[2] = a.z; t[3] = a.w;
      t[4] = bb.x; t[5] = bb.y; t[6] = bb.z; t[7] = bb.w;
      *(short8*)(xb + (size_t)idx * 8) = pack8(t);
    }
  } else {
    // sent: per-batch per-column mean of hidden (raw; route centers via Gram identity)
    int b2 = b - 19968;
    int batch = b2 & 31, part = b2 >> 5;
    int h = part * 256 + threadIdx.x;
    const float* p = hidden + (size_t)batch * Sn * Hn + h;
    float s = 0.f;
    for (int t = 0; t < Sn; t++) s += p[(size_t)t * Hn];
    cbuf[batch * Hn + h] = s * (1.f / (float)Sn);
  }
}

// ---------------- bf16 MFMA expert GEMM (m97 structure, BK=32 — verified r12) ----------------
// A bf16 [nbatch][512][lda]; Bt bf16 [E][N][K]; Y bf16 [nbatch][512][N].
// RES: 0 none, 1 f32 residual, 2 bf16 residual.
template <int ACT, int RES>
__global__ __launch_bounds__(256) void gemm_bt(
    const unsigned short* __restrict__ A, const unsigned short* __restrict__ Bt,
    const float* __restrict__ bias, const void* __restrict__ res,
    unsigned short* __restrict__ Y, const int* __restrict__ r,
    int K, int N, int lda, int bofs) {
  __shared__ __align__(16) unsigned short As[4096];  // 128 rows x 32 k
  __shared__ __align__(16) unsigned short Bs[4096];  // 128 cols x 32 k
  int z = blockIdx.z;
  int e = r[bofs + z];
  int tid = threadIdx.x;
  int wid = tid >> 6, lane = tid & 63;
  int wy = wid >> 1, wx = wid & 1;
  int lr = lane & 15, lg = lane >> 4;
  const unsigned short* Ab = A + (size_t)z * Sn * lda + (size_t)blockIdx.y * 128 * lda;
  const unsigned short* Bb = Bt + (size_t)e * N * K + (size_t)blockIdx.x * 128 * K;
  int r0 = wid * 16 + (lane >> 2);
  int r1 = (4 + wid) * 16 + (lane >> 2);
  int kk = (lane & 3) * 8;
  unsigned short* As0 = As + (size_t)wid * 512;
  unsigned short* As1 = As + (size_t)(4 + wid) * 512;
  unsigned short* Bs0 = Bs + (size_t)wid * 512;
  unsigned short* Bs1 = Bs + (size_t)(4 + wid) * 512;

  f32x4 acc[4][4];
#pragma unroll
  for (int m = 0; m < 4; m++)
#pragma unroll
    for (int n = 0; n < 4; n++) acc[m][n] = (f32x4){0.f, 0.f, 0.f, 0.f};

  for (int k0 = 0; k0 < K; k0 += 32) {
    gload16(Ab + (size_t)r0 * lda + k0 + kk, As0);
    gload16(Ab + (size_t)r1 * lda + k0 + kk, As1);
    gload16(Bb + (size_t)r0 * K + k0 + kk, Bs0);
    gload16(Bb + (size_t)r1 * K + k0 + kk, Bs1);
    __syncthreads();
    short8 af[4], bf[4];
#pragma unroll
    for (int m = 0; m < 4; m++) af[m] = *(const short8*)&As[(wy * 64 + m * 16 + lr) * 32 + lg * 8];
#pragma unroll
    for (int n = 0; n < 4; n++) bf[n] = *(const short8*)&Bs[(wx * 64 + n * 16 + lr) * 32 + lg * 8];
#pragma unroll
    for (int m = 0; m < 4; m++)
#pragma unroll
      for (int n = 0; n < 4; n++)
        acc[m][n] = __builtin_amdgcn_mfma_f32_16x16x32_bf16(af[m], bf[n], acc[m][n], 0, 0, 0);
    __syncthreads();
  }

  int row0 = blockIdx.y * 128 + wy * 64;
  int col0 = blockIdx.x * 128 + wx * 64;
#pragma unroll
  for (int m = 0; m < 4; m++) {
#pragma unroll
    for (int n = 0; n < 4; n++) {
      int col = col0 + n * 16 + lr;
      float bias_v = bias[e * N + col];
#pragma unroll
      for (int rr = 0; rr < 4; rr++) {
        int row = row0 + m * 16 + lg * 4 + rr;
        size_t off = ((size_t)z * Sn + row) * N + col;
        float v = acc[m][n][rr] + bias_v;
        if (RES == 1) v += ((const float*)res)[off];
        if (RES == 2) v += b2f(((const unsigned short*)res)[off]);
        if (ACT == 1) v = fast_gelu(v);
        Y[off] = f2b(v);
      }
    }
  }
}

// ---------------- 128x64-tile variant (for N-narrow GEMMs like W2: doubles block count) ----------------
// Same fragment math/accumulation order as gemm_bt -> bit-identical outputs.
template <int ACT, int RES>
__global__ __launch_bounds__(256) void gemm_bt64(
    const unsigned short* __restrict__ A, const unsigned short* __restrict__ Bt,
    const float* __restrict__ bias, const void* __restrict__ res,
    unsigned short* __restrict__ Y, const int* __restrict__ r,
    int K, int N, int lda, int bofs) {
  __shared__ __align__(16) unsigned short As[4096];  // 128 rows x 32 k
  __shared__ __align__(16) unsigned short Bs[2048];  // 64 cols x 32 k
  int z = blockIdx.z;
  int e = r[bofs + z];
  int tid = threadIdx.x;
  int wid = tid >> 6, lane = tid & 63;
  int wy = wid >> 1, wx = wid & 1;           // wave sub-tile: 64 rows x 32 cols
  int lr = lane & 15, lg = lane >> 4;
  const unsigned short* Ab = A + (size_t)z * Sn * lda + (size_t)blockIdx.y * 128 * lda;
  const unsigned short* Bb = Bt + (size_t)e * N * K + (size_t)blockIdx.x * 64 * K;
  int r0 = wid * 16 + (lane >> 2);           // 0..63 across wids
  int r1 = (4 + wid) * 16 + (lane >> 2);     // 64..127
  int kk = (lane & 3) * 8;
  unsigned short* As0 = As + (size_t)wid * 512;
  unsigned short* As1 = As + (size_t)(4 + wid) * 512;
  unsigned short* Bs0 = Bs + (size_t)wid * 512;   // rows 0..63 only

  f32x4 acc[4][2];
#pragma unroll
  for (int m = 0; m < 4; m++)
#pragma unroll
    for (int n = 0; n < 2; n++) acc[m][n] = (f32x4){0.f, 0.f, 0.f, 0.f};

  for (int k0 = 0; k0 < K; k0 += 32) {
    gload16(Ab + (size_t)r0 * lda + k0 + kk, As0);
    gload16(Ab + (size_t)r1 * lda + k0 + kk, As1);
    gload16(Bb + (size_t)r0 * K + k0 + kk, Bs0);
    __syncthreads();
    short8 af[4], bf[2];
#pragma unroll
    for (int m = 0; m < 4; m++) af[m] = *(const short8*)&As[(wy * 64 + m * 16 + lr) * 32 + lg * 8];
#pragma unroll
    for (int n = 0; n < 2; n++) bf[n] = *(const short8*)&Bs[(wx * 32 + n * 16 + lr) * 32 + lg * 8];
#pragma unroll
    for (int m = 0; m < 4; m++)
#pragma unroll
      for (int n = 0; n < 2; n++)
        acc[m][n] = __builtin_amdgcn_mfma_f32_16x16x32_bf16(af[m], bf[n], acc[m][n], 0, 0, 0);
    __syncthreads();
  }

  int row0 = blockIdx.y * 128 + wy * 64;
  int col0 = blockIdx.x * 64 + wx * 32;
#pragma unroll
  for (int m = 0; m < 4; m++) {
#pragma unroll
    for (int n = 0; n < 2; n++) {
      int col = col0 + n * 16 + lr;
      float bias_v = bias[e * N + col];
#pragma unroll
      for (int rr = 0; rr < 4; rr++) {
        int row = row0 + m * 16 + lg * 4 + rr;
        size_t off = ((size_t)z * Sn + row) * N + col;
        float v = acc[m][n][rr] + bias_v;
        if (RES == 1) v += ((const float*)res)[off];
        if (RES == 2) v += b2f(((const unsigned short*)res)[off]);
        if (ACT == 1) v = fast_gelu(v);
        Y[off] = f2b(v);
      }
    }
  }
}

// fused Q/K/V projection (BK=32): grid.z = 96, which = z>>5, batch = z&31
__global__ __launch_bounds__(256) void gemm_qkv(
    const unsigned short* __restrict__ A,
    const unsigned short* __restrict__ Wq, const unsigned short* __restrict__ Wk,
    const unsigned short* __restrict__ Wv,
    const float* __restrict__ bq, const float* __restrict__ bk, const float* __restrict__ bv,
    unsigned short* __restrict__ Oq, unsigned short* __restrict__ Ok, unsigned short* __restrict__ Ov,
    const int* __restrict__ r) {
  __shared__ __align__(16) unsigned short As[4096];
  __shared__ __align__(16) unsigned short Bs[4096];
  const int K = Hn, N = Hn, lda = Hn;
  int zz = blockIdx.z;
  int which = zz >> 5, z = zz & 31;
  const unsigned short* Bt = which == 0 ? Wq : which == 1 ? Wk : Wv;
  const float* bias = which == 0 ? bq : which == 1 ? bk : bv;
  unsigned short* Y = which == 0 ? Oq : which == 1 ? Ok : Ov;
  int e = r[z];
  int tid = threadIdx.x;
  int wid = tid >> 6, lane = tid & 63;
  int wy = wid >> 1, wx = wid & 1;
  int lr = lane & 15, lg = lane >> 4;
  const unsigned short* Ab = A + (size_t)z * Sn * lda + (size_t)blockIdx.y * 128 * lda;
  const unsigned short* Bb = Bt + (size_t)e * N * K + (size_t)blockIdx.x * 128 * K;
  int r0 = wid * 16 + (lane >> 2);
  int r1 = (4 + wid) * 16 + (lane >> 2);
  int kk = (lane & 3) * 8;
  unsigned short* As0 = As + (size_t)wid * 512;
  unsigned short* As1 = As + (size_t)(4 + wid) * 512;
  unsigned short* Bs0 = Bs + (size_t)wid * 512;
  unsigned short* Bs1 = Bs + (size_t)(4 + wid) * 512;

  f32x4 acc[4][4];
#pragma unroll
  for (int m = 0; m < 4; m++)
#pragma unroll
    for (int n = 0; n < 4; n++) acc[m][n] = (f32x4){0.f, 0.f, 0.f, 0.f};

  for (int k0 = 0; k0 < K; k0 += 32) {
    gload16(Ab + (size_t)r0 * lda + k0 + kk, As0);
    gload16(Ab + (size_t)r1 * lda + k0 + kk, As1);
    gload16(Bb + (size_t)r0 * K + k0 + kk, Bs0);
    gload16(Bb + (size_t)r1 * K + k0 + kk, Bs1);
    __syncthreads();
    short8 af[4], bf[4];
#pragma unroll
    for (int m = 0; m < 4; m++) af[m] = *(const short8*)&As[(wy * 64 + m * 16 + lr) * 32 + lg * 8];
#pragma unroll
    for (int n = 0; n < 4; n++) bf[n] = *(const short8*)&Bs[(wx * 64 + n * 16 + lr) * 32 + lg * 8];
#pragma unroll
    for (int m = 0; m < 4; m++)
#pragma unroll
      for (int n = 0; n < 4; n++)
        acc[m][n] = __builtin_amdgcn_mfma_f32_16x16x32_bf16(af[m], bf[n], acc[m][n], 0, 0, 0);
    __syncthreads();
  }

  int row0 = blockIdx.y * 128 + wy * 64;
  int col0 = blockIdx.x * 128 + wx * 64;
#pragma unroll
  for (int m = 0; m < 4; m++) {
#pragma unroll
    for (int n = 0; n < 4; n++) {
      int col = col0 + n * 16 + lr;
      float bias_v = bias[e * N + col];
#pragma unroll
      for (int rr = 0; rr < 4; rr++) {
        int row = row0 + m * 16 + lg * 4 + rr;
        size_t off = ((size_t)z * Sn + row) * N + col;
        Y[off] = f2b(acc[m][n][rr] + bias_v);
      }
    }
  }
}

// ---------------- MFMA flash attention (bf16 in/out), KVBLK=64 ----------------
__global__ __launch_bounds__(256) void attn_mfma(
    const unsigned short* qb, const unsigned short* __restrict__ kb,
    const unsigned short* __restrict__ vb, const float* __restrict__ amask,
    unsigned short* ctx) {
  __shared__ short Kl[64][72];
  __shared__ short Vt[64][72];
  __shared__ float mk[512];
  int qt = blockIdx.x, h = blockIdx.y, b = blockIdx.z;
  int tid = threadIdx.x, w = tid >> 6, lane = tid & 63;
  int lr = lane & 15, lg = lane >> 4;

  for (int i2 = tid; i2 < 512; i2 += 256) mk[i2] = (1.f - amask[b * Sn + i2]) * (-10000.f);

  int qrow = qt * 64 + w * 16 + lr;
  const unsigned short* qp = qb + ((size_t)(b * Sn + qrow)) * Hn + h * 64 + lg * 8;
  short8 qf0 = *(const short8*)qp;
  short8 qf1 = *(const short8*)(qp + 32);

  f32x4 o[4];
#pragma unroll
  for (int f = 0; f < 4; f++) o[f] = (f32x4){0.f, 0.f, 0.f, 0.f};
  float mrun = -3e38f, lsum = 0.f;

  for (int kv0 = 0; kv0 < Sn; kv0 += 64) {
    __syncthreads();
    {  // K tile [64][64] bf16: each thread loads 2 rows
      int kvr = tid >> 3, i8 = tid & 7;
      const unsigned short* kp = kb + ((size_t)(b * Sn + kv0 + kvr)) * Hn + h * 64 + i8 * 8;
      *(short8*)&Kl[kvr][i8 * 8] = *(const short8*)kp;
      *(short8*)&Kl[kvr + 32][i8 * 8] = *(const short8*)(kp + (size_t)32 * Hn);
    }
    {  // V^T tile [64 d][64 kv]: each thread packs 2 groups of 8 kv
      int d = tid & 63, kq = tid >> 6;
#pragma unroll
      for (int gq = 0; gq < 2; gq++) {
        int kvg = kq + gq * 4;
        const unsigned short* vp = vb + ((size_t)(b * Sn + kv0 + kvg * 8)) * Hn + h * 64 + d;
        unsigned a0 = (unsigned)vp[0] | ((unsigned)vp[Hn] << 16);
        unsigned a1 = (unsigned)vp[2 * Hn] | ((unsigned)vp[3 * Hn] << 16);
        unsigned a2 = (unsigned)vp[4 * Hn] | ((unsigned)vp[5 * Hn] << 16);
        unsigned a3 = (unsigned)vp[6 * Hn] | ((unsigned)vp[7 * Hn] << 16);
        int4v wv; wv.x = (int)a0; wv.y = (int)a1; wv.z = (int)a2; wv.w = (int)a3;
        *(short8*)&Vt[d][kvg * 8] = __builtin_bit_cast(short8, wv);
      }
    }
    __syncthreads();

    f32x4 s[4];
#pragma unroll
    for (int qq = 0; qq < 4; qq++) {
      s[qq] = (f32x4){0.f, 0.f, 0.f, 0.f};
      short8 ka = *(short8*)&Kl[qq * 16 + lr][lg * 8];
      short8 kc = *(short8*)&Kl[qq * 16 + lr][32 + lg * 8];
      s[qq] = __builtin_amdgcn_mfma_f32_16x16x32_bf16(ka, qf0, s[qq], 0, 0, 0);
      s[qq] = __builtin_amdgcn_mfma_f32_16x16x32_bf16(kc, qf1, s[qq], 0, 0, 0);
    }
#pragma unroll
    for (int qq = 0; qq < 4; qq++) {
      f32x4 mq = *(f32x4*)&mk[kv0 + qq * 16 + lg * 4];
#pragma unroll
      for (int rr = 0; rr < 4; rr++) s[qq][rr] = s[qq][rr] * 0.125f + mq[rr];
    }

    float pm = -1e30f;
#pragma unroll
    for (int qq = 0; qq < 4; qq++)
#pragma unroll
      for (int rr = 0; rr < 4; rr++) pm = fmaxf(pm, s[qq][rr]);
    pm = fmaxf(pm, __shfl_xor(pm, 16, 64));
    pm = fmaxf(pm, __shfl_xor(pm, 32, 64));
    float mn = fmaxf(mrun, pm);
    float al = __expf(mrun - mn);
    float p0[4], p1[4], p2[4], p3[4];
    float ls = 0.f;
#pragma unroll
    for (int rr = 0; rr < 4; rr++) { p0[rr] = __expf(s[0][rr] - mn); ls += p0[rr]; }
#pragma unroll
    for (int rr = 0; rr < 4; rr++) { p1[rr] = __expf(s[1][rr] - mn); ls += p1[rr]; }
#pragma unroll
    for (int rr = 0; rr < 4; rr++) { p2[rr] = __expf(s[2][rr] - mn); ls += p2[rr]; }
#pragma unroll
    for (int rr = 0; rr < 4; rr++) { p3[rr] = __expf(s[3][rr] - mn); ls += p3[rr]; }
    ls += __shfl_xor(ls, 16, 64);
    ls += __shfl_xor(ls, 32, 64);
    lsum = lsum * al + ls;
    mrun = mn;
#pragma unroll
    for (int f = 0; f < 4; f++)
#pragma unroll
      for (int rr = 0; rr < 4; rr++) o[f][rr] *= al;

    int srcA = lr + (((2 * lg) & 3) << 4);
    int srcB = srcA + 16;
    bool lo = lg < 2;
    short8 pf0, pf1;
    {
      unsigned a0p = packpair(p0[0], p0[1]), a1p = packpair(p0[2], p0[3]);
      unsigned b0p = packpair(p1[0], p1[1]), b1p = packpair(p1[2], p1[3]);
      unsigned xa0 = __shfl(a0p, srcA, 64), xa1 = __shfl(a1p, srcA, 64);
      unsigned xb0 = __shfl(b0p, srcA, 64), xb1 = __shfl(b1p, srcA, 64);
      unsigned ya0 = __shfl(a0p, srcB, 64), ya1 = __shfl(a1p, srcB, 64);
      unsigned yb0 = __shfl(b0p, srcB, 64), yb1 = __shfl(b1p, srcB, 64);
      int4v pw;
      pw.x = (int)(lo ? xa0 : xb0); pw.y = (int)(lo ? xa1 : xb1);
      pw.z = (int)(lo ? ya0 : yb0); pw.w = (int)(lo ? ya1 : yb1);
      pf0 = __builtin_bit_cast(short8, pw);
    }
    {
      unsigned a0p = packpair(p2[0], p2[1]), a1p = packpair(p2[2], p2[3]);
      unsigned b0p = packpair(p3[0], p3[1]), b1p = packpair(p3[2], p3[3]);
      unsigned xa0 = __shfl(a0p, srcA, 64), xa1 = __shfl(a1p, srcA, 64);
      unsigned xb0 = __shfl(b0p, srcA, 64), xb1 = __shfl(b1p, srcA, 64);
      unsigned ya0 = __shfl(a0p, srcB, 64), ya1 = __shfl(a1p, srcB, 64);
      unsigned yb0 = __shfl(b0p, srcB, 64), yb1 = __shfl(b1p, srcB, 64);
      int4v pw;
      pw.x = (int)(lo ? xa0 : xb0); pw.y = (int)(lo ? xa1 : xb1);
      pw.z = (int)(lo ? ya0 : yb0); pw.w = (int)(lo ? ya1 : yb1);
      pf1 = __builtin_bit_cast(short8, pw);
    }

#pragma unroll
    for (int f = 0; f < 4; f++) {
      short8 vf0 = *(short8*)&Vt[f * 16 + lr][lg * 8];
      short8 vf1 = *(short8*)&Vt[f * 16 + lr][32 + lg * 8];
      o[f] = __builtin_amdgcn_mfma_f32_16x16x32_bf16(vf0, pf0, o[f], 0, 0, 0);
      o[f] = __builtin_amdgcn_mfma_f32_16x16x32_bf16(vf1, pf1, o[f], 0, 0, 0);
    }
  }

  float inv = 1.f / lsum;
  unsigned short* op = ctx + ((size_t)(b * Sn + qt * 64 + w * 16 + lr)) * Hn + h * 64;
#pragma unroll
  for (int f = 0; f < 4; f++) {
    uint2 wv;
    wv.x = packpair(o[f][0] * inv, o[f][1] * inv);
    wv.y = packpair(o[f][2] * inv, o[f][3] * inv);
    *(uint2*)(op + f * 16 + lg * 4) = wv;
  }
}

// ---------------- layernorm (bf16 in; bf16 or f32 out) ----------------
template <int OUTF32>
__global__ __launch_bounds__(256) void ln_bf(const unsigned short* __restrict__ X, void* __restrict__ Yv,
    const float* __restrict__ gam, const float* __restrict__ bet, const int* __restrict__ r) {
  __shared__ float red1[4], red2[4];
  int row = blockIdx.x;
  int tid = threadIdx.x;
  const unsigned short* x = X + (size_t)row * Hn;
  float v0 = b2f(x[tid]), v1 = b2f(x[tid + 256]), v2 = b2f(x[tid + 512]);
  float s = v0 + v1 + v2;
#pragma unroll
  for (int o = 32; o; o >>= 1) s += __shfl_xor(s, o, 64);
  if ((tid & 63) == 0) red1[tid >> 6] = s;
  __syncthreads();
  float mu = (red1[0] + red1[1] + red1[2] + red1[3]) * (1.f / (float)Hn);
  float d0 = v0 - mu, d1 = v1 - mu, d2 = v2 - mu;
  float q = d0 * d0 + d1 * d1 + d2 * d2;
#pragma unroll
  for (int o = 32; o; o >>= 1) q += __shfl_xor(q, o, 64);
  if ((tid & 63) == 0) red2[tid >> 6] = q;
  __syncthreads();
  float var = (red2[0] + red2[1] + red2[2] + red2[3]) * (1.f / (float)Hn);
  float inv = rsqrtf(var + 1e-12f);
  int e = r[row >> 9];
  const float* g = gam + e * Hn;
  const float* be = bet + e * Hn;
  float o0 = d0 * inv * g[tid] + be[tid];
  float o1 = d1 * inv * g[tid + 256] + be[tid + 256];
  float o2 = d2 * inv * g[tid + 512] + be[tid + 512];
  if (OUTF32) {
    float* y = (float*)Yv + (size_t)row * Hn;
    y[tid] = o0; y[tid + 256] = o1; y[tid + 512] = o2;
  } else {
    unsigned short* y = (unsigned short*)Yv + (size_t)row * Hn;
    y[tid] = f2b(o0); y[tid + 256] = f2b(o1); y[tid + 512] = f2b(o2);
  }
}

// ---------------- launch ----------------
extern "C" void kernel_launch(void* const* d_in, const int* in_sizes, int n_in,
                              void* d_out, int out_size, void* d_ws, size_t ws_size,
                              hipStream_t stream) {
  const float* hidden = (const float*)d_in[0];
  const float* amask  = (const float*)d_in[1];
  const float* Wq = (const float*)d_in[2];
  const float* bq = (const float*)d_in[3];
  const float* Wk = (const float*)d_in[4];
  const float* bk = (const float*)d_in[5];
  const float* Wv = (const float*)d_in[6];
  const float* bv = (const float*)d_in[7];
  const float* Wo = (const float*)d_in[8];
  const float* bo = (const float*)d_in[9];
  const float* g1 = (const float*)d_in[10];
  const float* b1g = (const float*)d_in[11];
  const float* W1 = (const float*)d_in[12];
  const float* b1 = (const float*)d_in[13];
  const float* W2 = (const float*)d_in[14];
  const float* b2 = (const float*)d_in[15];
  const float* g2 = (const float*)d_in[16];
  const float* b2g = (const float*)d_in[17];
  float* out = (float*)d_out;

  char* w = (char*)d_ws;
  int* r = (int*)w;                              // 128 B
  float* cbuf = (float*)(w + 8192);              // 96 KB (raw sent means)
  const size_t TOK = (size_t)Bn * Sn;            // 16384
  size_t off = (size_t)1 << 20;
  const size_t WSML = (size_t)En * Hn * Hn * 2;        // 9.4 MB
  const size_t WBIG = (size_t)En * Hn * INTERn * 2;    // 37.7 MB
  const size_t ABUF = TOK * Hn * 2;                    // 25.2 MB
  unsigned short* Wqt = (unsigned short*)(w + off); off += WSML;
  unsigned short* Wkt = (unsigned short*)(w + off); off += WSML;
  unsigned short* Wvt = (unsigned short*)(w + off); off += WSML;
  unsigned short* Wot = (unsigned short*)(w + off); off += WSML;
  unsigned short* W1t = (unsigned short*)(w + off); off += WBIG;
  unsigned short* W2t = (unsigned short*)(w + off); off += WBIG;
  unsigned short* xb  = (unsigned short*)(w + off); off += ABUF;  // x_bf -> att_bf
  unsigned short* qb2 = (unsigned short*)(w + off); off += ABUF;  // q -> ctx
  unsigned short* kb2 = (unsigned short*)(w + off); off += ABUF;  // k -> ffn_pre
  unsigned short* vb2 = (unsigned short*)(w + off); off += ABUF;  // v -> h1 chunk (with pb)
  unsigned short* pb  = (unsigned short*)(w + off); off += ABUF;  // att_pre; part of h1 chunk
  // total ~229 MB. vb2+pb adjacent = 50 MB = h1 chunk for G=16.

  // conversions + sent (independent) — one wide kernel
  conv_kernel<<<20064, 256, 0, stream>>>(Wq, Wk, Wv, Wo, W1, W2,
                                         Wqt, Wkt, Wvt, Wot, W1t, W2t, hidden, xb, cbuf);

  // routing: raw-Gram centering inside route (no center kernel)
  route_kernel<<<1, 256, 0, stream>>>(cbuf, r);

  // fused q,k,v projections
  gemm_qkv<<<dim3(6, 4, 96), 256, 0, stream>>>(xb, Wqt, Wkt, Wvt, bq, bk, bv, qb2, kb2, vb2, r);

  // attention (ctx in-place over qb2)
  attn_mfma<<<dim3(8, 12, 32), 256, 0, stream>>>(qb2, kb2, vb2, amask, qb2);

  // output projection + f32 residual(hidden) -> pb (att_pre bf16); LN1 -> xb (att_bf)
  gemm_bt<0, 1><<<dim3(6, 4, 32), 256, 0, stream>>>(qb2, Wot, bo, hidden, pb, r, Hn, Hn, Hn, 0);
  ln_bf<0><<<16384, 256, 0, stream>>>(pb, xb, g1, b1g, r);

  // FFN chunked G=16: h1 chunk spans vb2+pb (both dead); ffn_pre -> kb2
  // W2 uses the 128x64-tile variant (N=768 -> 12 N-tiles, 768 blocks = 3/CU vs 1.5/CU)
  const int G = 16;
  unsigned short* h1c = vb2;  // 50 MB region (vb2..pb end)
  for (int c = 0; c < Bn / G; c++) {
    const unsigned short* attc = xb + (size_t)c * G * Sn * Hn;
    unsigned short* ffc = kb2 + (size_t)c * G * Sn * Hn;
    gemm_bt<1, 0><<<dim3(24, 4, G), 256, 0, stream>>>(attc, W1t, b1, nullptr, h1c, r, Hn, INTERn, Hn, c * G);
    gemm_bt64<0, 2><<<dim3(12, 4, G), 256, 0, stream>>>(h1c, W2t, b2, attc, ffc, r, INTERn, Hn, INTERn, c * G);
  }
  ln_bf<1><<<16384, 256, 0, stream>>>(kb2, out, g2, b2g, r);
}